// Round 4
// baseline (13852.174 us; speedup 1.0000x reference)
//
#include <hip/hip_runtime.h>

constexpr float LN_EPS = 1e-5f;

__device__ inline float hsum4(float4 v){ return v.x+v.y+v.z+v.w; }
__device__ inline float hdot4(float4 v){ return v.x*v.x+v.y*v.y+v.z*v.z+v.w*v.w; }
__device__ inline float4 f4add(float4 a, float4 b){ return make_float4(a.x+b.x,a.y+b.y,a.z+b.z,a.w+b.w); }
__device__ inline float4 lnrelu(float4 y, float mean, float rs, float4 g, float4 b){
  float4 o;
  o.x = fmaxf(fmaf((y.x-mean)*rs, g.x, b.x), 0.f);
  o.y = fmaxf(fmaf((y.y-mean)*rs, g.y, b.y), 0.f);
  o.z = fmaxf(fmaf((y.z-mean)*rs, g.z, b.z), 0.f);
  o.w = fmaxf(fmaf((y.w-mean)*rs, g.w, b.w), 0.f);
  return o;
}

// ---------------- input LayerNorm ----------------
__global__ __launch_bounds__(256) void input_ln_k(
    const float* __restrict__ h, const float* __restrict__ g,
    const float* __restrict__ b, float* __restrict__ out, int N){
  int w = blockIdx.x*(blockDim.x>>6) + (threadIdx.x>>6);
  if (w >= N) return;
  int lane = threadIdx.x & 63;
  float2 v = *(const float2*)(h + (long)w*128 + lane*2);
  float s = v.x+v.y, sq = v.x*v.x + v.y*v.y;
  #pragma unroll
  for (int x=1;x<64;x<<=1){ s += __shfl_xor(s,x); sq += __shfl_xor(sq,x); }
  float mean = s*(1.f/128.f), var = sq*(1.f/128.f) - mean*mean;
  float rs = rsqrtf(var + LN_EPS);
  float2 gv = *(const float2*)(g + lane*2), bv = *(const float2*)(b + lane*2);
  float2 o;
  o.x = fmaf((v.x-mean)*rs, gv.x, bv.x);
  o.y = fmaf((v.y-mean)*rs, gv.y, bv.y);
  *(float2*)(out + (long)w*128 + lane*2) = o;
}

// ---------------- edge scatter-add (GIN aggregation) ----------------
__global__ __launch_bounds__(256) void scatter_edges(
    const float* __restrict__ h, const int* __restrict__ src,
    const int* __restrict__ dst, float* __restrict__ agg, int E){
  long t = (long)blockIdx.x*blockDim.x + threadIdx.x;
  long e = t >> 7;
  if (e >= E) return;
  int c = (int)(t & 127);
  int s = src[e], d = dst[e];
  float v = h[(long)s*128 + c];
  atomicAdd(agg + (long)d*128 + c, v);
}

// ---------------- fused GEMM + bias + LN(+LN) + ReLU (+residual) ----------------
// MODE 0: z = A + A2;  out = relu(LN1(z@W + bias))
// MODE 1: z = A;       t = relu(LN1(z@W + bias)); u = relu(LN2(t)); out = u (+ resid)
// 512 threads per 128x128 tile: 32 outputs/thread keeps live VGPRs ~85 (<128,
// no spill). Row-parallel: block reads/writes only its own 128 rows -> in-place ok.
template<int MODE>
__global__ __launch_bounds__(512, 4) void gemm_fused(
    const float* __restrict__ A, const float* __restrict__ A2,
    const float* __restrict__ W, const float* __restrict__ bias,
    const float* __restrict__ g1v, const float* __restrict__ b1v,
    const float* __restrict__ g2v, const float* __restrict__ b2v,
    const float* __restrict__ resid,
    float* __restrict__ out, int N){
  __shared__ float Wlds[128][128];      // 64 KB
  __shared__ float Zlds[2][128][16];    // 16 KB double-buffered k-slices
  const int tid = threadIdx.x;
  {
    const float4* Wg = (const float4*)W;
    float4* Wl = (float4*)&Wlds[0][0];
    #pragma unroll
    for (int i=0;i<8;i++) Wl[i*512 + tid] = Wg[i*512 + tid];
  }

  const int wid = tid >> 6, lane = tid & 63;
  const int rg = lane >> 4, cg = lane & 15;
  const int c0 = cg*4, c1 = 64 + cg*4;
  const int blockBase = blockIdx.x*128;

  // staging role: thread t loads row (t>>2) at k-quad (t&3); LDS dst = tid*16B (linear)
  const int srow = tid >> 2, sq = tid & 3;

  auto stage_load = [&](int s) -> float4 {
    const int k0 = s*16 + sq*4;
    int r = blockBase + srow;
    if (r > N-1) r = N-1;
    float4 t = *(const float4*)(A + (size_t)r*128 + k0);
    if (MODE==0){
      float4 t2 = *(const float4*)(A2 + (size_t)r*128 + k0);
      t.x+=t2.x; t.y+=t2.y; t.z+=t2.z; t.w+=t2.w;
    }
    return t;
  };
  auto stage_write = [&](int buf, float4 v){
    *(float4*)(&Zlds[buf][srow][sq*4]) = v;
  };

  float4 acc[4], acc2[4];
  #pragma unroll
  for (int m=0;m<4;m++){ acc[m]=make_float4(0,0,0,0); acc2[m]=make_float4(0,0,0,0); }

  // rows owned by this lane: blockBase + wid*16 + m*4 + rg  (m=0..3)
  int lrow[4];
  #pragma unroll
  for (int m=0;m<4;m++) lrow[m] = wid*16 + m*4 + rg;

  auto comp = [&](int s, int buf){
    #pragma unroll
    for (int kc=0;kc<4;kc++){
      float4 z[4];
      #pragma unroll
      for (int m=0;m<4;m++)
        z[m] = *(const float4*)(&Zlds[buf][lrow[m]][kc*4]);
      #pragma unroll
      for (int kk=0;kk<4;kk++){
        const int kg = s*16 + kc*4 + kk;
        const float4 w0 = *(const float4*)&Wlds[kg][c0];
        const float4 w1 = *(const float4*)&Wlds[kg][c1];
        #pragma unroll
        for (int m=0;m<4;m++){
          float zv = (kk==0)?z[m].x:(kk==1)?z[m].y:(kk==2)?z[m].z:z[m].w;
          acc[m].x  = fmaf(zv, w0.x, acc[m].x);
          acc[m].y  = fmaf(zv, w0.y, acc[m].y);
          acc[m].z  = fmaf(zv, w0.z, acc[m].z);
          acc[m].w  = fmaf(zv, w0.w, acc[m].w);
          acc2[m].x = fmaf(zv, w1.x, acc2[m].x);
          acc2[m].y = fmaf(zv, w1.y, acc2[m].y);
          acc2[m].z = fmaf(zv, w1.z, acc2[m].z);
          acc2[m].w = fmaf(zv, w1.w, acc2[m].w);
        }
      }
    }
  };

  stage_write(0, stage_load(0));
  __syncthreads();   // W tile + slice 0 visible

  #pragma unroll 1
  for (int s=0; s<8; ++s){
    float4 nx;
    if (s < 7) nx = stage_load(s+1);      // issue loads early; latency hides under comp
    comp(s, s & 1);
    if (s < 7) stage_write((s+1)&1, nx);  // other waves done reading this buf at step s-1
    __syncthreads();                      // writes visible before step s+1 comp
  }

  // ---- epilogue ----
  const float4 bi0 = *(const float4*)(bias + c0), bi1 = *(const float4*)(bias + c1);
  const float4 g10 = *(const float4*)(g1v + c0), g11 = *(const float4*)(g1v + c1);
  const float4 b10 = *(const float4*)(b1v + c0), b11 = *(const float4*)(b1v + c1);
  float4 g20, g21, b20, b21;
  if (MODE==1){
    g20 = *(const float4*)(g2v + c0); g21 = *(const float4*)(g2v + c1);
    b20 = *(const float4*)(b2v + c0); b21 = *(const float4*)(b2v + c1);
  }

  #pragma unroll
  for (int m=0;m<4;m++){
    int r = blockBase + lrow[m];
    int rc = (r > N-1) ? N-1 : r;
    size_t off = (size_t)rc*128;
    float4 y0 = f4add(acc[m], bi0);
    float4 y1 = f4add(acc2[m], bi1);
    float s = hsum4(y0)+hsum4(y1);
    float sq = hdot4(y0)+hdot4(y1);
    #pragma unroll
    for (int x=1;x<16;x<<=1){ s += __shfl_xor(s,x); sq += __shfl_xor(sq,x); }
    float mean = s*(1.f/128.f);
    float var  = sq*(1.f/128.f) - mean*mean;
    float rs = rsqrtf(var + LN_EPS);
    float4 t0 = lnrelu(y0, mean, rs, g10, b10);
    float4 t1 = lnrelu(y1, mean, rs, g11, b11);
    if (MODE==1){
      float s2 = hsum4(t0)+hsum4(t1);
      float sq2 = hdot4(t0)+hdot4(t1);
      #pragma unroll
      for (int x=1;x<16;x<<=1){ s2 += __shfl_xor(s2,x); sq2 += __shfl_xor(sq2,x); }
      float mean2 = s2*(1.f/128.f);
      float var2  = sq2*(1.f/128.f) - mean2*mean2;
      float rs2 = rsqrtf(var2 + LN_EPS);
      t0 = lnrelu(t0, mean2, rs2, g20, b20);
      t1 = lnrelu(t1, mean2, rs2, g21, b21);
      if (resid){
        float4 r0 = *(const float4*)(resid + off + c0);
        float4 r1 = *(const float4*)(resid + off + c1);
        t0 = f4add(t0, r0); t1 = f4add(t1, r1);
      }
    }
    if (r < N){
      *(float4*)(out + off + c0) = t0;
      *(float4*)(out + off + c1) = t1;
    }
  }
}

// ---------------- pooling over sorted graph_ids ----------------
__global__ __launch_bounds__(256) void pool_k(
    const float* __restrict__ h, const int* __restrict__ gids,
    float* __restrict__ sums, float* __restrict__ counts, int N){
  const int CHUNK = 256;
  int w = blockIdx.x*(blockDim.x>>6) + (threadIdx.x>>6);
  int lane = threadIdx.x & 63;
  int n0 = w*CHUNK; if (n0 >= N) return;
  int n1 = min(n0+CHUNK, N);
  float2 acc = make_float2(0.f,0.f); float cnt = 0.f;
  int gprev = gids[n0];
  for (int n=n0; n<n1; ++n){
    int g = gids[n];
    if (g != gprev){
      atomicAdd(sums + (long)gprev*128 + lane*2,     acc.x);
      atomicAdd(sums + (long)gprev*128 + lane*2 + 1, acc.y);
      if (lane==0) atomicAdd(counts + gprev, cnt);
      acc = make_float2(0.f,0.f); cnt = 0.f; gprev = g;
    }
    float2 v = *(const float2*)(h + (long)n*128 + lane*2);
    acc.x += v.x; acc.y += v.y; cnt += 1.f;
  }
  atomicAdd(sums + (long)gprev*128 + lane*2,     acc.x);
  atomicAdd(sums + (long)gprev*128 + lane*2 + 1, acc.y);
  if (lane==0) atomicAdd(counts + gprev, cnt);
}

__global__ __launch_bounds__(256) void norm_k(
    const float* __restrict__ sums, const float* __restrict__ counts,
    float* __restrict__ out, int GD){
  int i = blockIdx.x*blockDim.x + threadIdx.x;
  if (i >= GD) return;
  float c = counts[i>>7];
  out[i] = sums[i] / fmaxf(c, 1.0f);
}

extern "C" void kernel_launch(void* const* d_in, const int* in_sizes, int n_in,
                              void* d_out, int out_size, void* d_ws, size_t ws_size,
                              hipStream_t stream) {
  const float* h_in  = (const float*)d_in[0];
  const int*   src   = (const int*)d_in[1];
  const int*   dst   = (const int*)d_in[2];
  const int*   gids  = (const int*)d_in[3];
  const float* ilng  = (const float*)d_in[4];
  const float* ilnb  = (const float*)d_in[5];
  const float* W1    = (const float*)d_in[6];
  const float* b1    = (const float*)d_in[7];
  const float* ln1g  = (const float*)d_in[8];
  const float* ln1b  = (const float*)d_in[9];
  const float* W2    = (const float*)d_in[10];
  const float* b2    = (const float*)d_in[11];
  const float* ln2g  = (const float*)d_in[12];
  const float* ln2b  = (const float*)d_in[13];
  const float* ng    = (const float*)d_in[14];
  const float* nb    = (const float*)d_in[15];

  const int N = in_sizes[0] / 128;
  const int E = in_sizes[1];
  const int G = out_size / 128;
  const int L = in_sizes[6] / (128*128);

  float* bufA   = (float*)d_ws;
  float* bufB   = bufA + (size_t)N*128;
  float* sums   = bufB + (size_t)N*128;
  float* counts = sums + (size_t)G*128;

  // h = LN(h_in)
  input_ln_k<<<(N+3)/4, 256, 0, stream>>>(h_in, ilng, ilnb, bufA, N);

  float* hcur = bufA;
  float* tmp  = bufB;
  const int gblocks = (N + 127)/128;
  const int sblocks = (int)(((long)E*128 + 255)/256);

  for (int i=0;i<L;i++){
    hipMemsetAsync(tmp, 0, (size_t)N*128*sizeof(float), stream);
    scatter_edges<<<sblocks, 256, 0, stream>>>(hcur, src, dst, tmp, E);
    gemm_fused<0><<<gblocks, 512, 0, stream>>>(
        hcur, tmp, W1 + (size_t)i*128*128, b1 + i*128,
        ln1g + i*128, ln1b + i*128, nullptr, nullptr, nullptr, tmp, N);
    gemm_fused<1><<<gblocks, 512, 0, stream>>>(
        tmp, nullptr, W2 + (size_t)i*128*128, b2 + i*128,
        ln2g + i*128, ln2b + i*128, ng + i*128, nb + i*128,
        (i>0) ? hcur : nullptr, tmp, N);
    float* t2 = hcur; hcur = tmp; tmp = t2;
  }

  // pooling
  hipMemsetAsync(sums, 0, ((size_t)G*128 + G)*sizeof(float), stream);
  int pw = (N + 255)/256;               // waves
  int pblocks = (pw + 3)/4;
  pool_k<<<pblocks, 256, 0, stream>>>(hcur, gids, sums, counts, N);
  norm_k<<<(G*128 + 255)/256, 256, 0, stream>>>(sums, counts, (float*)d_out, G*128);
}

// Round 6
// 3143.718 us; speedup vs baseline: 4.4063x; 4.4063x over previous
//
#include <hip/hip_runtime.h>

constexpr float LN_EPS = 1e-5f;

__device__ inline float hsum4(float4 v){ return v.x+v.y+v.z+v.w; }
__device__ inline float hdot4(float4 v){ return v.x*v.x+v.y*v.y+v.z*v.z+v.w*v.w; }
__device__ inline float4 f4add(float4 a, float4 b){ return make_float4(a.x+b.x,a.y+b.y,a.z+b.z,a.w+b.w); }
__device__ inline float4 lnrelu(float4 y, float mean, float rs, float4 g, float4 b){
  float4 o;
  o.x = fmaxf(fmaf((y.x-mean)*rs, g.x, b.x), 0.f);
  o.y = fmaxf(fmaf((y.y-mean)*rs, g.y, b.y), 0.f);
  o.z = fmaxf(fmaf((y.z-mean)*rs, g.z, b.z), 0.f);
  o.w = fmaxf(fmaf((y.w-mean)*rs, g.w, b.w), 0.f);
  return o;
}

// ---------------- input LayerNorm ----------------
__global__ __launch_bounds__(256) void input_ln_k(
    const float* __restrict__ h, const float* __restrict__ g,
    const float* __restrict__ b, float* __restrict__ out, int N){
  int w = blockIdx.x*(blockDim.x>>6) + (threadIdx.x>>6);
  if (w >= N) return;
  int lane = threadIdx.x & 63;
  float2 v = *(const float2*)(h + (long)w*128 + lane*2);
  float s = v.x+v.y, sq = v.x*v.x + v.y*v.y;
  #pragma unroll
  for (int x=1;x<64;x<<=1){ s += __shfl_xor(s,x); sq += __shfl_xor(sq,x); }
  float mean = s*(1.f/128.f), var = sq*(1.f/128.f) - mean*mean;
  float rs = rsqrtf(var + LN_EPS);
  float2 gv = *(const float2*)(g + lane*2), bv = *(const float2*)(b + lane*2);
  float2 o;
  o.x = fmaf((v.x-mean)*rs, gv.x, bv.x);
  o.y = fmaf((v.y-mean)*rs, gv.y, bv.y);
  *(float2*)(out + (long)w*128 + lane*2) = o;
}

// ---------------- edge scatter-add (GIN aggregation) ----------------
__global__ __launch_bounds__(256) void scatter_edges(
    const float* __restrict__ h, const int* __restrict__ src,
    const int* __restrict__ dst, float* __restrict__ agg, int E){
  long t = (long)blockIdx.x*blockDim.x + threadIdx.x;
  long e = t >> 7;
  if (e >= E) return;
  int c = (int)(t & 127);
  int s = src[e], d = dst[e];
  float v = h[(long)s*128 + c];
  atomicAdd(agg + (long)d*128 + c, v);
}

// ---------------- fused GEMM + bias + LN(+LN) + ReLU (+residual) ----------------
// MODE 0: z = A + A2;  out = relu(LN1(z@W + bias))
// MODE 1: z = A;       t = relu(LN1(z@W + bias)); u = relu(LN2(t)); out = u (+ resid)
// 512 threads per 128x128 tile: 32 outputs/thread, live VGPRs ~85.
// __launch_bounds__(512,2): hipcc VGPR cap = 256/minwaves -> 128 regs (no spill);
// (512,4) capped at 64 and spilled the accumulators (R4: 4.4 GB scratch writes).
// Row-parallel: block reads/writes only its own 128 rows -> in-place ok.
template<int MODE>
__global__ __launch_bounds__(512, 2) void gemm_fused(
    const float* __restrict__ A, const float* __restrict__ A2,
    const float* __restrict__ W, const float* __restrict__ bias,
    const float* __restrict__ g1v, const float* __restrict__ b1v,
    const float* __restrict__ g2v, const float* __restrict__ b2v,
    const float* __restrict__ resid,
    float* __restrict__ out, int N){
  __shared__ float Wlds[128][128];      // 64 KB
  __shared__ float Zlds[2][128][16];    // 16 KB double-buffered k-slices
  const int tid = threadIdx.x;
  {
    const float4* Wg = (const float4*)W;
    float4* Wl = (float4*)&Wlds[0][0];
    #pragma unroll
    for (int i=0;i<8;i++) Wl[i*512 + tid] = Wg[i*512 + tid];
  }

  const int wid = tid >> 6, lane = tid & 63;
  const int rg = lane >> 4, cg = lane & 15;
  const int c0 = cg*4, c1 = 64 + cg*4;
  const int blockBase = blockIdx.x*128;

  // staging role: thread t loads row (t>>2) at k-quad (t&3); LDS dst = tid*16B (linear)
  const int srow = tid >> 2, sq = tid & 3;

  auto stage_load = [&](int s) -> float4 {
    const int k0 = s*16 + sq*4;
    int r = blockBase + srow;
    if (r > N-1) r = N-1;
    float4 t = *(const float4*)(A + (size_t)r*128 + k0);
    if (MODE==0){
      float4 t2 = *(const float4*)(A2 + (size_t)r*128 + k0);
      t.x+=t2.x; t.y+=t2.y; t.z+=t2.z; t.w+=t2.w;
    }
    return t;
  };
  auto stage_write = [&](int buf, float4 v){
    *(float4*)(&Zlds[buf][srow][sq*4]) = v;
  };

  float4 acc[4], acc2[4];
  #pragma unroll
  for (int m=0;m<4;m++){ acc[m]=make_float4(0,0,0,0); acc2[m]=make_float4(0,0,0,0); }

  // rows owned by this lane: blockBase + wid*16 + m*4 + rg  (m=0..3)
  int lrow[4];
  #pragma unroll
  for (int m=0;m<4;m++) lrow[m] = wid*16 + m*4 + rg;

  auto comp = [&](int s, int buf){
    #pragma unroll
    for (int kc=0;kc<4;kc++){
      float4 z[4];
      #pragma unroll
      for (int m=0;m<4;m++)
        z[m] = *(const float4*)(&Zlds[buf][lrow[m]][kc*4]);
      #pragma unroll
      for (int kk=0;kk<4;kk++){
        const int kg = s*16 + kc*4 + kk;
        const float4 w0 = *(const float4*)&Wlds[kg][c0];
        const float4 w1 = *(const float4*)&Wlds[kg][c1];
        #pragma unroll
        for (int m=0;m<4;m++){
          float zv = (kk==0)?z[m].x:(kk==1)?z[m].y:(kk==2)?z[m].z:z[m].w;
          acc[m].x  = fmaf(zv, w0.x, acc[m].x);
          acc[m].y  = fmaf(zv, w0.y, acc[m].y);
          acc[m].z  = fmaf(zv, w0.z, acc[m].z);
          acc[m].w  = fmaf(zv, w0.w, acc[m].w);
          acc2[m].x = fmaf(zv, w1.x, acc2[m].x);
          acc2[m].y = fmaf(zv, w1.y, acc2[m].y);
          acc2[m].z = fmaf(zv, w1.z, acc2[m].z);
          acc2[m].w = fmaf(zv, w1.w, acc2[m].w);
        }
      }
    }
  };

  stage_write(0, stage_load(0));
  __syncthreads();   // W tile + slice 0 visible

  #pragma unroll 1
  for (int s=0; s<8; ++s){
    float4 nx;
    if (s < 7) nx = stage_load(s+1);      // issue loads early; latency hides under comp
    comp(s, s & 1);
    if (s < 7) stage_write((s+1)&1, nx);  // other waves done reading this buf at step s-1
    __syncthreads();                      // writes visible before step s+1 comp
  }

  // ---- epilogue ----
  const float4 bi0 = *(const float4*)(bias + c0), bi1 = *(const float4*)(bias + c1);
  const float4 g10 = *(const float4*)(g1v + c0), g11 = *(const float4*)(g1v + c1);
  const float4 b10 = *(const float4*)(b1v + c0), b11 = *(const float4*)(b1v + c1);
  float4 g20, g21, b20, b21;
  if (MODE==1){
    g20 = *(const float4*)(g2v + c0); g21 = *(const float4*)(g2v + c1);
    b20 = *(const float4*)(b2v + c0); b21 = *(const float4*)(b2v + c1);
  }

  #pragma unroll
  for (int m=0;m<4;m++){
    int r = blockBase + lrow[m];
    int rc = (r > N-1) ? N-1 : r;
    size_t off = (size_t)rc*128;
    float4 y0 = f4add(acc[m], bi0);
    float4 y1 = f4add(acc2[m], bi1);
    float s = hsum4(y0)+hsum4(y1);
    float sq = hdot4(y0)+hdot4(y1);
    #pragma unroll
    for (int x=1;x<16;x<<=1){ s += __shfl_xor(s,x); sq += __shfl_xor(sq,x); }
    float mean = s*(1.f/128.f);
    float var  = sq*(1.f/128.f) - mean*mean;
    float rs = rsqrtf(var + LN_EPS);
    float4 t0 = lnrelu(y0, mean, rs, g10, b10);
    float4 t1 = lnrelu(y1, mean, rs, g11, b11);
    if (MODE==1){
      float s2 = hsum4(t0)+hsum4(t1);
      float sq2 = hdot4(t0)+hdot4(t1);
      #pragma unroll
      for (int x=1;x<16;x<<=1){ s2 += __shfl_xor(s2,x); sq2 += __shfl_xor(sq2,x); }
      float mean2 = s2*(1.f/128.f);
      float var2  = sq2*(1.f/128.f) - mean2*mean2;
      float rs2 = rsqrtf(var2 + LN_EPS);
      t0 = lnrelu(t0, mean2, rs2, g20, b20);
      t1 = lnrelu(t1, mean2, rs2, g21, b21);
      if (resid){
        float4 r0 = *(const float4*)(resid + off + c0);
        float4 r1 = *(const float4*)(resid + off + c1);
        t0 = f4add(t0, r0); t1 = f4add(t1, r1);
      }
    }
    if (r < N){
      *(float4*)(out + off + c0) = t0;
      *(float4*)(out + off + c1) = t1;
    }
  }
}

// ---------------- pooling over sorted graph_ids ----------------
__global__ __launch_bounds__(256) void pool_k(
    const float* __restrict__ h, const int* __restrict__ gids,
    float* __restrict__ sums, float* __restrict__ counts, int N){
  const int CHUNK = 256;
  int w = blockIdx.x*(blockDim.x>>6) + (threadIdx.x>>6);
  int lane = threadIdx.x & 63;
  int n0 = w*CHUNK; if (n0 >= N) return;
  int n1 = min(n0+CHUNK, N);
  float2 acc = make_float2(0.f,0.f); float cnt = 0.f;
  int gprev = gids[n0];
  for (int n=n0; n<n1; ++n){
    int g = gids[n];
    if (g != gprev){
      atomicAdd(sums + (long)gprev*128 + lane*2,     acc.x);
      atomicAdd(sums + (long)gprev*128 + lane*2 + 1, acc.y);
      if (lane==0) atomicAdd(counts + gprev, cnt);
      acc = make_float2(0.f,0.f); cnt = 0.f; gprev = g;
    }
    float2 v = *(const float2*)(h + (long)n*128 + lane*2);
    acc.x += v.x; acc.y += v.y; cnt += 1.f;
  }
  atomicAdd(sums + (long)gprev*128 + lane*2,     acc.x);
  atomicAdd(sums + (long)gprev*128 + lane*2 + 1, acc.y);
  if (lane==0) atomicAdd(counts + gprev, cnt);
}

__global__ __launch_bounds__(256) void norm_k(
    const float* __restrict__ sums, const float* __restrict__ counts,
    float* __restrict__ out, int GD){
  int i = blockIdx.x*blockDim.x + threadIdx.x;
  if (i >= GD) return;
  float c = counts[i>>7];
  out[i] = sums[i] / fmaxf(c, 1.0f);
}

extern "C" void kernel_launch(void* const* d_in, const int* in_sizes, int n_in,
                              void* d_out, int out_size, void* d_ws, size_t ws_size,
                              hipStream_t stream) {
  const float* h_in  = (const float*)d_in[0];
  const int*   src   = (const int*)d_in[1];
  const int*   dst   = (const int*)d_in[2];
  const int*   gids  = (const int*)d_in[3];
  const float* ilng  = (const float*)d_in[4];
  const float* ilnb  = (const float*)d_in[5];
  const float* W1    = (const float*)d_in[6];
  const float* b1    = (const float*)d_in[7];
  const float* ln1g  = (const float*)d_in[8];
  const float* ln1b  = (const float*)d_in[9];
  const float* W2    = (const float*)d_in[10];
  const float* b2    = (const float*)d_in[11];
  const float* ln2g  = (const float*)d_in[12];
  const float* ln2b  = (const float*)d_in[13];
  const float* ng    = (const float*)d_in[14];
  const float* nb    = (const float*)d_in[15];

  const int N = in_sizes[0] / 128;
  const int E = in_sizes[1];
  const int G = out_size / 128;
  const int L = in_sizes[6] / (128*128);

  float* bufA   = (float*)d_ws;
  float* bufB   = bufA + (size_t)N*128;
  float* sums   = bufB + (size_t)N*128;
  float* counts = sums + (size_t)G*128;

  // h = LN(h_in)
  input_ln_k<<<(N+3)/4, 256, 0, stream>>>(h_in, ilng, ilnb, bufA, N);

  float* hcur = bufA;
  float* tmp  = bufB;
  const int gblocks = (N + 127)/128;
  const int sblocks = (int)(((long)E*128 + 255)/256);

  for (int i=0;i<L;i++){
    hipMemsetAsync(tmp, 0, (size_t)N*128*sizeof(float), stream);
    scatter_edges<<<sblocks, 256, 0, stream>>>(hcur, src, dst, tmp, E);
    gemm_fused<0><<<gblocks, 512, 0, stream>>>(
        hcur, tmp, W1 + (size_t)i*128*128, b1 + i*128,
        ln1g + i*128, ln1b + i*128, nullptr, nullptr, nullptr, tmp, N);
    gemm_fused<1><<<gblocks, 512, 0, stream>>>(
        tmp, nullptr, W2 + (size_t)i*128*128, b2 + i*128,
        ln2g + i*128, ln2b + i*128, ng + i*128, nb + i*128,
        (i>0) ? hcur : nullptr, tmp, N);
    float* t2 = hcur; hcur = tmp; tmp = t2;
  }

  // pooling
  hipMemsetAsync(sums, 0, ((size_t)G*128 + G)*sizeof(float), stream);
  int pw = (N + 255)/256;               // waves
  int pblocks = (pw + 3)/4;
  pool_k<<<pblocks, 256, 0, stream>>>(hcur, gids, sums, counts, N);
  norm_k<<<(G*128 + 255)/256, 256, 0, stream>>>(sums, counts, (float*)d_out, G*128);
}

// Round 9
// 2395.435 us; speedup vs baseline: 5.7827x; 1.3124x over previous
//
#include <hip/hip_runtime.h>

constexpr float LN_EPS = 1e-5f;

__device__ inline float hsum4(float4 v){ return v.x+v.y+v.z+v.w; }
__device__ inline float hdot4(float4 v){ return v.x*v.x+v.y*v.y+v.z*v.z+v.w*v.w; }
__device__ inline float4 f4add(float4 a, float4 b){ return make_float4(a.x+b.x,a.y+b.y,a.z+b.z,a.w+b.w); }
__device__ inline float4 lnrelu(float4 y, float mean, float rs, float4 g, float4 b){
  float4 o;
  o.x = fmaxf(fmaf((y.x-mean)*rs, g.x, b.x), 0.f);
  o.y = fmaxf(fmaf((y.y-mean)*rs, g.y, b.y), 0.f);
  o.z = fmaxf(fmaf((y.z-mean)*rs, g.z, b.z), 0.f);
  o.w = fmaxf(fmaf((y.w-mean)*rs, g.w, b.w), 0.f);
  return o;
}

// ---------------- input LayerNorm ----------------
__global__ __launch_bounds__(256) void input_ln_k(
    const float* __restrict__ h, const float* __restrict__ g,
    const float* __restrict__ b, float* __restrict__ out, int N){
  int w = blockIdx.x*(blockDim.x>>6) + (threadIdx.x>>6);
  if (w >= N) return;
  int lane = threadIdx.x & 63;
  float2 v = *(const float2*)(h + (long)w*128 + lane*2);
  float s = v.x+v.y, sq = v.x*v.x + v.y*v.y;
  #pragma unroll
  for (int x=1;x<64;x<<=1){ s += __shfl_xor(s,x); sq += __shfl_xor(sq,x); }
  float mean = s*(1.f/128.f), var = sq*(1.f/128.f) - mean*mean;
  float rs = rsqrtf(var + LN_EPS);
  float2 gv = *(const float2*)(g + lane*2), bv = *(const float2*)(b + lane*2);
  float2 o;
  o.x = fmaf((v.x-mean)*rs, gv.x, bv.x);
  o.y = fmaf((v.y-mean)*rs, gv.y, bv.y);
  *(float2*)(out + (long)w*128 + lane*2) = o;
}

// ---------------- CSR build (dst is loop-invariant: build once per launch) ----
__global__ __launch_bounds__(256) void hist_k(
    const int* __restrict__ dst, int* __restrict__ deg, int E){
  int e = blockIdx.x*256 + threadIdx.x;
  if (e < E) atomicAdd(deg + dst[e], 1);
}

// exclusive scan, 3-phase, 1024 elements/block
__global__ __launch_bounds__(256) void scan1_k(
    const int* __restrict__ deg, int* __restrict__ rp, int* __restrict__ btot, int N){
  __shared__ int wsum[4];
  const int t = threadIdx.x, lane = t & 63, wid = t >> 6;
  const int base = blockIdx.x*1024 + t*4;
  int d0=0,d1=0,d2=0,d3=0;
  if (base+3 < N){ int4 v = *(const int4*)(deg+base); d0=v.x; d1=v.y; d2=v.z; d3=v.w; }
  else {
    if (base   < N) d0 = deg[base];
    if (base+1 < N) d1 = deg[base+1];
    if (base+2 < N) d2 = deg[base+2];
    if (base+3 < N) d3 = deg[base+3];
  }
  const int s = d0+d1+d2+d3;
  int v = s;
  #pragma unroll
  for (int off=1; off<64; off<<=1){ int u = __shfl_up(v, off); if (lane>=off) v += u; }
  if (lane==63) wsum[wid] = v;
  __syncthreads();
  int wexcl = 0;
  #pragma unroll
  for (int i=0;i<4;i++) if (i < wid) wexcl += wsum[i];
  const int excl = wexcl + v - s;
  if (base   < N) rp[base]   = excl;
  if (base+1 < N) rp[base+1] = excl + d0;
  if (base+2 < N) rp[base+2] = excl + d0+d1;
  if (base+3 < N) rp[base+3] = excl + d0+d1+d2;
  if (t==255) btot[blockIdx.x] = wexcl + v;
}

__global__ __launch_bounds__(256) void scan2_k(
    int* __restrict__ btot, int nblk, int* __restrict__ rp, int N, int E){
  __shared__ int wsum[4];
  const int t = threadIdx.x, lane = t & 63, wid = t >> 6;
  const int base = t*8;
  int d[8]; int s = 0;
  #pragma unroll
  for (int k=0;k<8;k++){ d[k] = (base+k < nblk) ? btot[base+k] : 0; s += d[k]; }
  int v = s;
  #pragma unroll
  for (int off=1; off<64; off<<=1){ int u = __shfl_up(v, off); if (lane>=off) v += u; }
  if (lane==63) wsum[wid] = v;
  __syncthreads();
  int wexcl = 0;
  #pragma unroll
  for (int i=0;i<4;i++) if (i < wid) wexcl += wsum[i];
  int run = wexcl + v - s;
  #pragma unroll
  for (int k=0;k<8;k++){ if (base+k < nblk) btot[base+k] = run; run += d[k]; }
  if (t==0) rp[N] = E;
}

__global__ __launch_bounds__(256) void scan3_k(
    int* __restrict__ rp, const int* __restrict__ btot, int N){
  const int add = btot[blockIdx.x];
  if (add == 0) return;
  const int base = blockIdx.x*1024 + threadIdx.x*4;
  if (base+3 < N){
    int4 v = *(const int4*)(rp+base);
    v.x+=add; v.y+=add; v.z+=add; v.w+=add;
    *(int4*)(rp+base) = v;
  } else {
    for (int k=0;k<4;k++) if (base+k < N) rp[base+k] += add;
  }
}

__global__ __launch_bounds__(256) void fill_k(
    const int* __restrict__ src, const int* __restrict__ dst,
    int* __restrict__ cursor, int* __restrict__ eidx, int E){
  int e = blockIdx.x*256 + threadIdx.x;
  if (e >= E) return;
  int d = dst[e];
  int pos = atomicAdd(cursor + d, 1);
  eidx[pos] = src[e];
}

// ---------------- GIN aggregation via CSR gather: z[n] = h[n] + sum h[src] ----
__global__ __launch_bounds__(256) void gather_k(
    const float* __restrict__ h, const int* __restrict__ rp,
    const int* __restrict__ eidx, float* __restrict__ z, int N){
  int n = blockIdx.x*4 + (threadIdx.x>>6);
  if (n >= N) return;
  const int lane = threadIdx.x & 63;
  float2 a = *(const float2*)(h + (size_t)n*128 + lane*2);
  const int j0 = rp[n], j1 = rp[n+1];
  for (int j=j0; j<j1; ++j){
    int s = eidx[j];
    float2 v = *(const float2*)(h + (size_t)s*128 + lane*2);
    a.x += v.x; a.y += v.y;
  }
  *(float2*)(z + (size_t)n*128 + lane*2) = a;
}

// ---------------- fused GEMM + bias + LN(+LN) + ReLU (+residual) ----------------
// MODE 0: out = relu(LN1(A@W + bias))
// MODE 1: t = relu(LN1(A@W + bias)); out = relu(LN2(t)) (+ resid)
// 512 threads per 128x128 tile: 32 outputs/thread, live VGPRs ~85.
// __launch_bounds__(512,2): hipcc VGPR cap = 256/minwaves -> 128 regs (no spill);
// (512,4) capped at 64 and spilled the accumulators (R4: 4.4 GB scratch writes).
// Row-parallel: block reads/writes only its own 128 rows -> in-place ok.
template<int MODE>
__global__ __launch_bounds__(512, 2) void gemm_fused(
    const float* __restrict__ A,
    const float* __restrict__ W, const float* __restrict__ bias,
    const float* __restrict__ g1v, const float* __restrict__ b1v,
    const float* __restrict__ g2v, const float* __restrict__ b2v,
    const float* __restrict__ resid,
    float* __restrict__ out, int N){
  __shared__ float Wlds[128][128];      // 64 KB
  __shared__ float Zlds[2][128][16];    // 16 KB double-buffered k-slices
  const int tid = threadIdx.x;
  {
    const float4* Wg = (const float4*)W;
    float4* Wl = (float4*)&Wlds[0][0];
    #pragma unroll
    for (int i=0;i<8;i++) Wl[i*512 + tid] = Wg[i*512 + tid];
  }

  const int wid = tid >> 6, lane = tid & 63;
  const int rg = lane >> 4, cg = lane & 15;
  const int c0 = cg*4, c1 = 64 + cg*4;
  const int blockBase = blockIdx.x*128;

  // staging role: thread t loads row (t>>2) at k-quad (t&3); LDS dst = tid*16B (linear)
  const int srow = tid >> 2, sq = tid & 3;

  auto stage_load = [&](int s) -> float4 {
    const int k0 = s*16 + sq*4;
    int r = blockBase + srow;
    if (r > N-1) r = N-1;
    return *(const float4*)(A + (size_t)r*128 + k0);
  };
  auto stage_write = [&](int buf, float4 v){
    *(float4*)(&Zlds[buf][srow][sq*4]) = v;
  };

  float4 acc[4], acc2[4];
  #pragma unroll
  for (int m=0;m<4;m++){ acc[m]=make_float4(0,0,0,0); acc2[m]=make_float4(0,0,0,0); }

  // rows owned by this lane: blockBase + wid*16 + m*4 + rg  (m=0..3)
  int lrow[4];
  #pragma unroll
  for (int m=0;m<4;m++) lrow[m] = wid*16 + m*4 + rg;

  auto comp = [&](int s, int buf){
    #pragma unroll
    for (int kc=0;kc<4;kc++){
      float4 z[4];
      #pragma unroll
      for (int m=0;m<4;m++)
        z[m] = *(const float4*)(&Zlds[buf][lrow[m]][kc*4]);
      #pragma unroll
      for (int kk=0;kk<4;kk++){
        const int kg = s*16 + kc*4 + kk;
        const float4 w0 = *(const float4*)&Wlds[kg][c0];
        const float4 w1 = *(const float4*)&Wlds[kg][c1];
        #pragma unroll
        for (int m=0;m<4;m++){
          float zv = (kk==0)?z[m].x:(kk==1)?z[m].y:(kk==2)?z[m].z:z[m].w;
          acc[m].x  = fmaf(zv, w0.x, acc[m].x);
          acc[m].y  = fmaf(zv, w0.y, acc[m].y);
          acc[m].z  = fmaf(zv, w0.z, acc[m].z);
          acc[m].w  = fmaf(zv, w0.w, acc[m].w);
          acc2[m].x = fmaf(zv, w1.x, acc2[m].x);
          acc2[m].y = fmaf(zv, w1.y, acc2[m].y);
          acc2[m].z = fmaf(zv, w1.z, acc2[m].z);
          acc2[m].w = fmaf(zv, w1.w, acc2[m].w);
        }
      }
    }
  };

  stage_write(0, stage_load(0));
  __syncthreads();   // W tile + slice 0 visible

  #pragma unroll 1
  for (int s=0; s<8; ++s){
    float4 nx;
    if (s < 7) nx = stage_load(s+1);      // issue loads early; latency hides under comp
    comp(s, s & 1);
    if (s < 7) stage_write((s+1)&1, nx);  // other waves done reading this buf at step s-1
    __syncthreads();                      // writes visible before step s+1 comp
  }

  // ---- epilogue ----
  const float4 bi0 = *(const float4*)(bias + c0), bi1 = *(const float4*)(bias + c1);
  const float4 g10 = *(const float4*)(g1v + c0), g11 = *(const float4*)(g1v + c1);
  const float4 b10 = *(const float4*)(b1v + c0), b11 = *(const float4*)(b1v + c1);
  float4 g20, g21, b20, b21;
  if (MODE==1){
    g20 = *(const float4*)(g2v + c0); g21 = *(const float4*)(g2v + c1);
    b20 = *(const float4*)(b2v + c0); b21 = *(const float4*)(b2v + c1);
  }

  #pragma unroll
  for (int m=0;m<4;m++){
    int r = blockBase + lrow[m];
    int rc = (r > N-1) ? N-1 : r;
    size_t off = (size_t)rc*128;
    float4 y0 = f4add(acc[m], bi0);
    float4 y1 = f4add(acc2[m], bi1);
    float s = hsum4(y0)+hsum4(y1);
    float sq = hdot4(y0)+hdot4(y1);
    #pragma unroll
    for (int x=1;x<16;x<<=1){ s += __shfl_xor(s,x); sq += __shfl_xor(sq,x); }
    float mean = s*(1.f/128.f);
    float var  = sq*(1.f/128.f) - mean*mean;
    float rs = rsqrtf(var + LN_EPS);
    float4 t0 = lnrelu(y0, mean, rs, g10, b10);
    float4 t1 = lnrelu(y1, mean, rs, g11, b11);
    if (MODE==1){
      float s2 = hsum4(t0)+hsum4(t1);
      float sq2 = hdot4(t0)+hdot4(t1);
      #pragma unroll
      for (int x=1;x<16;x<<=1){ s2 += __shfl_xor(s2,x); sq2 += __shfl_xor(sq2,x); }
      float mean2 = s2*(1.f/128.f);
      float var2  = sq2*(1.f/128.f) - mean2*mean2;
      float rs2 = rsqrtf(var2 + LN_EPS);
      t0 = lnrelu(t0, mean2, rs2, g20, b20);
      t1 = lnrelu(t1, mean2, rs2, g21, b21);
      if (resid){
        float4 r0 = *(const float4*)(resid + off + c0);
        float4 r1 = *(const float4*)(resid + off + c1);
        t0 = f4add(t0, r0); t1 = f4add(t1, r1);
      }
    }
    if (r < N){
      *(float4*)(out + off + c0) = t0;
      *(float4*)(out + off + c1) = t1;
    }
  }
}

// ---------------- pooling over sorted graph_ids ----------------
__global__ __launch_bounds__(256) void pool_k(
    const float* __restrict__ h, const int* __restrict__ gids,
    float* __restrict__ sums, float* __restrict__ counts, int N){
  const int CHUNK = 256;
  int w = blockIdx.x*(blockDim.x>>6) + (threadIdx.x>>6);
  int lane = threadIdx.x & 63;
  int n0 = w*CHUNK; if (n0 >= N) return;
  int n1 = min(n0+CHUNK, N);
  float2 acc = make_float2(0.f,0.f); float cnt = 0.f;
  int gprev = gids[n0];
  for (int n=n0; n<n1; ++n){
    int g = gids[n];
    if (g != gprev){
      atomicAdd(sums + (long)gprev*128 + lane*2,     acc.x);
      atomicAdd(sums + (long)gprev*128 + lane*2 + 1, acc.y);
      if (lane==0) atomicAdd(counts + gprev, cnt);
      acc = make_float2(0.f,0.f); cnt = 0.f; gprev = g;
    }
    float2 v = *(const float2*)(h + (long)n*128 + lane*2);
    acc.x += v.x; acc.y += v.y; cnt += 1.f;
  }
  atomicAdd(sums + (long)gprev*128 + lane*2,     acc.x);
  atomicAdd(sums + (long)gprev*128 + lane*2 + 1, acc.y);
  if (lane==0) atomicAdd(counts + gprev, cnt);
}

__global__ __launch_bounds__(256) void norm_k(
    const float* __restrict__ sums, const float* __restrict__ counts,
    float* __restrict__ out, int GD){
  int i = blockIdx.x*blockDim.x + threadIdx.x;
  if (i >= GD) return;
  float c = counts[i>>7];
  out[i] = sums[i] / fmaxf(c, 1.0f);
}

extern "C" void kernel_launch(void* const* d_in, const int* in_sizes, int n_in,
                              void* d_out, int out_size, void* d_ws, size_t ws_size,
                              hipStream_t stream) {
  const float* h_in  = (const float*)d_in[0];
  const int*   src   = (const int*)d_in[1];
  const int*   dst   = (const int*)d_in[2];
  const int*   gids  = (const int*)d_in[3];
  const float* ilng  = (const float*)d_in[4];
  const float* ilnb  = (const float*)d_in[5];
  const float* W1    = (const float*)d_in[6];
  const float* b1    = (const float*)d_in[7];
  const float* ln1g  = (const float*)d_in[8];
  const float* ln1b  = (const float*)d_in[9];
  const float* W2    = (const float*)d_in[10];
  const float* b2    = (const float*)d_in[11];
  const float* ln2g  = (const float*)d_in[12];
  const float* ln2b  = (const float*)d_in[13];
  const float* ng    = (const float*)d_in[14];
  const float* nrmb  = (const float*)d_in[15];

  const int N = in_sizes[0] / 128;
  const int E = in_sizes[1];
  const int G = out_size / 128;
  const int L = in_sizes[6] / (128*128);

  float* bufA   = (float*)d_ws;
  float* bufB   = bufA + (size_t)N*128;
  float* sums   = bufB + (size_t)N*128;
  float* counts = sums + (size_t)G*128;
  int*   rowptr = (int*)(counts + G);          // N+1
  int*   cursor = rowptr + (N+1);              // N (deg, then fill cursor)
  int*   btot   = cursor + N;                  // <=2048 block sums
  int*   eidx   = btot + 2048;                 // E (src per CSR slot)

  const int nblk = (N + 1023)/1024;

  // ---- CSR build (dst/src invariant across layers) ----
  hipMemsetAsync(cursor, 0, (size_t)N*sizeof(int), stream);
  hist_k<<<(E+255)/256, 256, 0, stream>>>(dst, cursor, E);
  scan1_k<<<nblk, 256, 0, stream>>>(cursor, rowptr, btot, N);
  scan2_k<<<1, 256, 0, stream>>>(btot, nblk, rowptr, N, E);
  scan3_k<<<nblk, 256, 0, stream>>>(rowptr, btot, N);
  hipMemcpyAsync(cursor, rowptr, (size_t)N*sizeof(int),
                 hipMemcpyDeviceToDevice, stream);
  fill_k<<<(E+255)/256, 256, 0, stream>>>(src, dst, cursor, eidx, E);

  // ---- h = LN(h_in) ----
  input_ln_k<<<(N+3)/4, 256, 0, stream>>>(h_in, ilng, ilnb, bufA, N);

  float* hcur = bufA;
  float* tmp  = bufB;
  const int gblocks = (N + 127)/128;

  for (int i=0;i<L;i++){
    gather_k<<<(N+3)/4, 256, 0, stream>>>(hcur, rowptr, eidx, tmp, N);
    gemm_fused<0><<<gblocks, 512, 0, stream>>>(
        tmp, W1 + (size_t)i*128*128, b1 + i*128,
        ln1g + i*128, ln1b + i*128, nullptr, nullptr, nullptr, tmp, N);
    gemm_fused<1><<<gblocks, 512, 0, stream>>>(
        tmp, W2 + (size_t)i*128*128, b2 + i*128,
        ln2g + i*128, ln2b + i*128, ng + i*128, nrmb + i*128,
        (i>0) ? hcur : nullptr, tmp, N);
    float* t2 = hcur; hcur = tmp; tmp = t2;
  }

  // ---- pooling ----
  hipMemsetAsync(sums, 0, ((size_t)G*128 + G)*sizeof(float), stream);
  int pw = (N + 255)/256;               // waves
  int pblocks = (pw + 3)/4;
  pool_k<<<pblocks, 256, 0, stream>>>(hcur, gids, sums, counts, N);
  norm_k<<<(G*128 + 255)/256, 256, 0, stream>>>(sums, counts, (float*)d_out, G*128);
}